// Round 13
// baseline (410.946 us; speedup 1.0000x reference)
//
#include <hip/hip_runtime.h>
#include <math.h>

#define Nn 8192
#define Cc 256
#define Dd 128
#define CAP 192   // max row degree: mean ~83, max over 8192 rows ~125

typedef float fx4 __attribute__((ext_vector_type(4)));

// ---------------- W transpose: WT[c4*128 + d] = W[d][4c4..4c4+3] -----------
__global__ __launch_bounds__(256) void wt_kernel(const float* __restrict__ W,
                                                 float4* __restrict__ WT) {
  const int t = blockIdx.x * 256 + threadIdx.x;  // 0..8191
  const int c4 = t >> 7;
  const int d  = t & 127;
  const float4 v = *(const float4*)(W + (size_t)d * Cc + c4 * 4);
  WT[c4 * Dd + d] = v;
}

// ---------------- h = x @ W^T (via WT, all loads coalesced/broadcast) ------
__global__ __launch_bounds__(256) void h_kernel(const float* __restrict__ x,
                                                const float4* __restrict__ WT,
                                                float* __restrict__ h) {
  const int tid = threadIdx.x;
  const int d = tid & 127;
  const int g = tid >> 7;
  const int r0 = blockIdx.x * 16 + g * 8;
  const float4* x4 = (const float4*)(x + (size_t)r0 * Cc);

  float acc[8];
#pragma unroll
  for (int r = 0; r < 8; ++r) acc[r] = 0.f;

#pragma unroll 4
  for (int c4 = 0; c4 < Cc / 4; ++c4) {
    const float4 w = WT[c4 * Dd + d];        // coalesced 16B/lane
#pragma unroll
    for (int r = 0; r < 8; ++r) {
      const float4 u = x4[r * (Cc / 4) + c4];  // wave-uniform broadcast
      acc[r] += u.x * w.x + u.y * w.y + u.z * w.z + u.w * w.w;
    }
  }
#pragma unroll
  for (int r = 0; r < 8; ++r) {
    h[(size_t)(r0 + r) * Dd + d] = acc[r];
  }
}

// One compaction group (one fx4 component across the wave)
#define COMPACT(comp, cidx)                                             \
  {                                                                     \
    const unsigned long long mk = __ballot((comp) != 0.f);              \
    if (mk) {                                                           \
      const int p = cnt + __popcll(mk & lmask);                         \
      if ((comp) != 0.f && p < CAP) idx[p] = col + (cidx);              \
      cnt += __popcll(mk);                                              \
    }                                                                   \
  }

// One online-softmax step: 4 edges (one per 16-lane quarter)
__device__ __forceinline__ void tail_step(int s, int m, const int* idx, int i,
                                          const float* __restrict__ h,
                                          int q, int ql,
                                          const float4& hiA, const float4& hiB,
                                          float& M, float& L,
                                          float4& accA, float4& accB) {
  const int e = s * 4 + q;
  const int j = (e < m) ? idx[e] : i;            // safe dummy row
  const float4 hvA = *(const float4*)(h + (size_t)j * Dd + ql * 8);
  const float4 hvB = *(const float4*)(h + (size_t)j * Dd + ql * 8 + 4);
  float pd = hiA.x * hvA.x + hiA.y * hvA.y + hiA.z * hvA.z + hiA.w * hvA.w
           + hiB.x * hvB.x + hiB.y * hvB.y + hiB.z * hvB.z + hiB.w * hvB.w;
#pragma unroll
  for (int off = 8; off > 0; off >>= 1) pd += __shfl_xor(pd, off);  // quarters separate
  const float sc = (e < m) ? pd : 0.f;
  if (sc != 0.f) {                               // ref: s==0 -> masked
    const float newM = fmaxf(M, sc);
    const float scale = __expf(M - newM);        // first edge: exp(-inf)=0
    const float p = __expf(sc - newM);
    L = L * scale + p;
    accA.x = accA.x * scale + p * hvA.x;  accA.y = accA.y * scale + p * hvA.y;
    accA.z = accA.z * scale + p * hvA.z;  accA.w = accA.w * scale + p * hvA.w;
    accB.x = accB.x * scale + p * hvB.x;  accB.y = accB.y * scale + p * hvB.y;
    accB.z = accB.z * scale + p * hvB.z;  accB.w = accB.w * scale + p * hvB.w;
    M = newM;
  }
}

// Merge quarter states (xor16 then xor32) and write the row (lanes q==0)
__device__ __forceinline__ void merge_write(int i, const float* __restrict__ bias,
                                            float* __restrict__ out, int q, int ql,
                                            float M, float L, float4 accA, float4 accB) {
#pragma unroll
  for (int off = 16; off <= 32; off <<= 1) {
    const float Mo = __shfl_xor(M, off);
    const float Lo = __shfl_xor(L, off);
    float4 aAo, aBo;
    aAo.x = __shfl_xor(accA.x, off); aAo.y = __shfl_xor(accA.y, off);
    aAo.z = __shfl_xor(accA.z, off); aAo.w = __shfl_xor(accA.w, off);
    aBo.x = __shfl_xor(accB.x, off); aBo.y = __shfl_xor(accB.y, off);
    aBo.z = __shfl_xor(accB.z, off); aBo.w = __shfl_xor(accB.w, off);
    const float Mm = fmaxf(M, Mo);
    const float s0 = (M  > -INFINITY) ? __expf(M  - Mm) : 0.f;  // empty-quarter guard
    const float s1 = (Mo > -INFINITY) ? __expf(Mo - Mm) : 0.f;
    L = L * s0 + Lo * s1;
    accA.x = accA.x * s0 + aAo.x * s1;  accA.y = accA.y * s0 + aAo.y * s1;
    accA.z = accA.z * s0 + aAo.z * s1;  accA.w = accA.w * s0 + aAo.w * s1;
    accB.x = accB.x * s0 + aBo.x * s1;  accB.y = accB.y * s0 + aBo.y * s1;
    accB.z = accB.z * s0 + aBo.z * s1;  accB.w = accB.w * s0 + aBo.w * s1;
    M = Mm;
  }
  const float inv = 1.f / L;
  if (q == 0) {
    const float4 bA = *(const float4*)(bias + ql * 8);
    const float4 bB = *(const float4*)(bias + ql * 8 + 4);
    float4 oA, oB;
    oA.x = accA.x * inv + bA.x;  oA.y = accA.y * inv + bA.y;
    oA.z = accA.z * inv + bA.z;  oA.w = accA.w * inv + bA.w;
    oB.x = accB.x * inv + bB.x;  oB.y = accB.y * inv + bB.y;
    oB.z = accB.z * inv + bB.z;  oB.w = accB.w * inv + bB.w;
    *(float4*)(out + (size_t)i * Dd + ql * 8)     = oA;
    *(float4*)(out + (size_t)i * Dd + ql * 8 + 4) = oB;
  }
}

// ---------------- FUSED, 2 ROWS PER WAVE, cross-row pipelined --------------
// Wave streams+compacts row A; then streams row B with one tail-A step
// interleaved after every compaction group (tail-A hides under B's NT
// prefetch). Only tail-B (+ A leftovers) is exposed. Single cohort:
// 1024 blocks = 4 waves/SIMD exactly.
__global__ __launch_bounds__(256, 4) void gat_fused(const float* __restrict__ graph,
                                                    const float* __restrict__ h,
                                                    const float* __restrict__ bias,
                                                    float* __restrict__ out) {
  __shared__ int idxs[8][CAP];
  const int wv   = threadIdx.x >> 6;
  const int lane = threadIdx.x & 63;
  const int q    = lane >> 4;
  const int ql   = lane & 15;
  const int iA = blockIdx.x * 8 + wv * 2;
  const int iB = iA + 1;
  int* idxA = idxs[wv * 2];
  int* idxB = idxs[wv * 2 + 1];
  const unsigned long long lmask = (1ull << lane) - 1ull;

  const float4 hiA_A = *(const float4*)(h + (size_t)iA * Dd + ql * 8);
  const float4 hiB_A = *(const float4*)(h + (size_t)iA * Dd + ql * 8 + 4);
  const float4 hiA_B = *(const float4*)(h + (size_t)iB * Dd + ql * 8);
  const float4 hiB_B = *(const float4*)(h + (size_t)iB * Dd + ql * 8 + 4);

  // ---- Phase 1A: stream + compact row A (rolling 8-deep NT prefetch) ----
  int mA;
  {
    const fx4* row = (const fx4*)(graph + (size_t)iA * Nn);
    int* idx = idxA;
    int cnt = 0;
    fx4 v[8];
#pragma unroll
    for (int t = 0; t < 8; ++t)
      v[t] = __builtin_nontemporal_load(&row[t * 64 + lane]);
#pragma unroll
    for (int c = 0; c < 4; ++c) {
#pragma unroll
      for (int t = 0; t < 8; ++t) {
        const fx4 cur = v[t];
        if (c < 3)
          v[t] = __builtin_nontemporal_load(&row[(c + 1) * 8 * 64 + t * 64 + lane]);
        const int col = 4 * ((c * 8 + t) * 64 + lane);
        COMPACT(cur.x, 0) COMPACT(cur.y, 1) COMPACT(cur.z, 2) COMPACT(cur.w, 3)
      }
    }
    mA = min(cnt, CAP);
  }

  // ---- tail-A state ----
  float MA = -INFINITY, LA = 0.f;
  float4 accA_A = {0.f, 0.f, 0.f, 0.f}, accB_A = {0.f, 0.f, 0.f, 0.f};
  int sA = 0;
  const int nsA = (mA + 3) >> 2;

  // ---- Phase 1B: stream + compact row B, tail-A interleaved ----
  int mB;
  {
    const fx4* row = (const fx4*)(graph + (size_t)iB * Nn);
    int* idx = idxB;
    int cnt = 0;
    fx4 v[8];
#pragma unroll
    for (int t = 0; t < 8; ++t)
      v[t] = __builtin_nontemporal_load(&row[t * 64 + lane]);
#pragma unroll
    for (int c = 0; c < 4; ++c) {
#pragma unroll
      for (int t = 0; t < 8; ++t) {
        const fx4 cur = v[t];
        if (c < 3)
          v[t] = __builtin_nontemporal_load(&row[(c + 1) * 8 * 64 + t * 64 + lane]);
        const int col = 4 * ((c * 8 + t) * 64 + lane);
        COMPACT(cur.x, 0) COMPACT(cur.y, 1) COMPACT(cur.z, 2) COMPACT(cur.w, 3)
        // one tail-A step hides under B's in-flight NT loads
        if (sA < nsA) {
          tail_step(sA, mA, idxA, iA, h, q, ql, hiA_A, hiB_A, MA, LA, accA_A, accB_A);
          ++sA;
        }
      }
    }
    mB = min(cnt, CAP);
  }

  // ---- tail-A leftovers (m > 128 only), merge + write A ----
  for (; sA < nsA; ++sA)
    tail_step(sA, mA, idxA, iA, h, q, ql, hiA_A, hiB_A, MA, LA, accA_A, accB_A);
  merge_write(iA, bias, out, q, ql, MA, LA, accA_A, accB_A);

  // ---- tail B (exposed once per 2 rows), merge + write B ----
  float MB = -INFINITY, LB = 0.f;
  float4 accA_B = {0.f, 0.f, 0.f, 0.f}, accB_B = {0.f, 0.f, 0.f, 0.f};
  const int nsB = (mB + 3) >> 2;
  for (int s = 0; s < nsB; ++s)
    tail_step(s, mB, idxB, iB, h, q, ql, hiA_B, hiB_B, MB, LB, accA_B, accB_B);
  merge_write(iB, bias, out, q, ql, MB, LB, accA_B, accB_B);
}

extern "C" void kernel_launch(void* const* d_in, const int* in_sizes, int n_in,
                              void* d_out, int out_size, void* d_ws, size_t ws_size,
                              hipStream_t stream) {
  const float* x     = (const float*)d_in[0];  // [1,8192,256]
  const float* graph = (const float*)d_in[1];  // [8192,8192]
  const float* W     = (const float*)d_in[2];  // [128,256]
  const float* bias  = (const float*)d_in[3];  // [128]
  float* out = (float*)d_out;                  // [1,8192,128]

  // ws layout: h (4 MB @ 0) | WT (128 KB @ 16 MB)
  float*  h  = (float*)d_ws;
  float4* WT = (float4*)((char*)d_ws + (16u << 20));

  wt_kernel<<<32, 256, 0, stream>>>(W, WT);
  h_kernel<<<Nn / 16, 256, 0, stream>>>(x, WT, h);
  gat_fused<<<Nn / 8, 256, 0, stream>>>(graph, h, bias, out);
}

// Round 14
// 401.256 us; speedup vs baseline: 1.0241x; 1.0241x over previous
//
#include <hip/hip_runtime.h>
#include <math.h>

#define Nn 8192
#define Cc 256
#define Dd 128
#define CAP 192   // max row degree: mean ~83, max over 8192 rows ~125

typedef float fx4 __attribute__((ext_vector_type(4)));

// DPP rotation-add within each 16-lane row (quarter): lane l += lane (l+N)%16.
// Rotations 8,4,2,1 give sum-to-all in 4 VALU instrs (no DS pipe, no shfl).
template <int CTRL>
__device__ __forceinline__ float dpp_radd(float x) {
  const int y = __builtin_amdgcn_update_dpp(0, __float_as_int(x), CTRL, 0xf, 0xf, false);
  return x + __int_as_float(y);
}
__device__ __forceinline__ float quarter_sum(float x) {
  x = dpp_radd<0x128>(x);  // row_ror:8
  x = dpp_radd<0x124>(x);  // row_ror:4
  x = dpp_radd<0x122>(x);  // row_ror:2
  x = dpp_radd<0x121>(x);  // row_ror:1
  return x;
}

// ---------------- W transpose: WT[c4*128 + d] = W[d][4c4..4c4+3] -----------
__global__ __launch_bounds__(256) void wt_kernel(const float* __restrict__ W,
                                                 float4* __restrict__ WT) {
  const int t = blockIdx.x * 256 + threadIdx.x;  // 0..8191
  const int c4 = t >> 7;
  const int d  = t & 127;
  const float4 v = *(const float4*)(W + (size_t)d * Cc + c4 * 4);
  WT[c4 * Dd + d] = v;
}

// ---------------- h = x @ W^T (via WT, all loads coalesced/broadcast) ------
__global__ __launch_bounds__(256) void h_kernel(const float* __restrict__ x,
                                                const float4* __restrict__ WT,
                                                float* __restrict__ h) {
  const int tid = threadIdx.x;
  const int d = tid & 127;
  const int g = tid >> 7;
  const int r0 = blockIdx.x * 16 + g * 8;
  const float4* x4 = (const float4*)(x + (size_t)r0 * Cc);

  float acc[8];
#pragma unroll
  for (int r = 0; r < 8; ++r) acc[r] = 0.f;

#pragma unroll 4
  for (int c4 = 0; c4 < Cc / 4; ++c4) {
    const float4 w = WT[c4 * Dd + d];        // coalesced 16B/lane
#pragma unroll
    for (int r = 0; r < 8; ++r) {
      const float4 u = x4[r * (Cc / 4) + c4];  // wave-uniform broadcast
      acc[r] += u.x * w.x + u.y * w.y + u.z * w.z + u.w * w.w;
    }
  }
#pragma unroll
  for (int r = 0; r < 8; ++r) {
    h[(size_t)(r0 + r) * Dd + d] = acc[r];
  }
}

// ---------------- FUSED: NT-stream graph row -> ballot compact (LDS idx)
//                  -> quarter-wave online-softmax tail (DPP reduction) ------
// One wave per row. Phase 1: rolling 8-deep NT prefetch + ballot compaction
// (NT also protects h's L3 residency from the 268 MB stream — removing NT
// measured +47 us in r8). Phase 2: 4 edges/step (one per 16-lane quarter),
// DPP rotation-reduce for the dot, batch=4 steps with next-batch prefetch
// (16 edges in flight) to cover L2/L3 h-load latency.
__global__ __launch_bounds__(256, 4) void gat_fused(const float* __restrict__ graph,
                                                    const float* __restrict__ h,
                                                    const float* __restrict__ bias,
                                                    float* __restrict__ out) {
  __shared__ int idxs[4][CAP];
  const int wv   = threadIdx.x >> 6;
  const int lane = threadIdx.x & 63;
  const int q    = lane >> 4;          // quarter 0..3 (edge slot within step)
  const int ql   = lane & 15;          // float8 slot: elements ql*8 .. ql*8+7
  const int i = blockIdx.x * 4 + wv;
  int* idx = idxs[wv];

  const float4 hiA = *(const float4*)(h + (size_t)i * Dd + ql * 8);
  const float4 hiB = *(const float4*)(h + (size_t)i * Dd + ql * 8 + 4);

  // ---- Phase 1: NT stream + ballot compact, rolling 8-deep prefetch ----
  const fx4* row = (const fx4*)(graph + (size_t)i * Nn);
  const unsigned long long lmask = (1ull << lane) - 1ull;
  int cnt = 0;  // wave-uniform (SGPR)

  fx4 v[8];
#pragma unroll
  for (int t = 0; t < 8; ++t)
    v[t] = __builtin_nontemporal_load(&row[t * 64 + lane]);

#pragma unroll
  for (int c = 0; c < 4; ++c) {
#pragma unroll
    for (int t = 0; t < 8; ++t) {
      const fx4 cur = v[t];
      if (c < 3)
        v[t] = __builtin_nontemporal_load(&row[(c + 1) * 8 * 64 + t * 64 + lane]);
      const int col = 4 * ((c * 8 + t) * 64 + lane);
      {
        const unsigned long long mk = __ballot(cur.x != 0.f);
        if (mk) {
          const int p = cnt + __popcll(mk & lmask);
          if (cur.x != 0.f && p < CAP) idx[p] = col + 0;
          cnt += __popcll(mk);
        }
      }
      {
        const unsigned long long mk = __ballot(cur.y != 0.f);
        if (mk) {
          const int p = cnt + __popcll(mk & lmask);
          if (cur.y != 0.f && p < CAP) idx[p] = col + 1;
          cnt += __popcll(mk);
        }
      }
      {
        const unsigned long long mk = __ballot(cur.z != 0.f);
        if (mk) {
          const int p = cnt + __popcll(mk & lmask);
          if (cur.z != 0.f && p < CAP) idx[p] = col + 2;
          cnt += __popcll(mk);
        }
      }
      {
        const unsigned long long mk = __ballot(cur.w != 0.f);
        if (mk) {
          const int p = cnt + __popcll(mk & lmask);
          if (cur.w != 0.f && p < CAP) idx[p] = col + 3;
          cnt += __popcll(mk);
        }
      }
    }
  }
  const int m = min(cnt, CAP);

  // ---- Phase 2: quarter-wave online softmax, batch=4 steps + prefetch ----
  float M = -INFINITY, L = 0.f;
  float4 accA = {0.f, 0.f, 0.f, 0.f};
  float4 accB = {0.f, 0.f, 0.f, 0.f};

  const int nsteps = (m + 3) >> 2;     // step s covers edges s*4 + q
  const int nb = (nsteps + 3) >> 2;    // batches of 4 steps

  float4 hvA[4], hvB[4];
#pragma unroll
  for (int u = 0; u < 4; ++u) {
    const int e = u * 4 + q;
    const int j = (e < m) ? idx[e] : i;          // safe dummy row
    hvA[u] = *(const float4*)(h + (size_t)j * Dd + ql * 8);
    hvB[u] = *(const float4*)(h + (size_t)j * Dd + ql * 8 + 4);
  }

  for (int b = 0; b < nb; ++b) {
    float4 nA[4], nB[4];
    if (b + 1 < nb) {
#pragma unroll
      for (int u = 0; u < 4; ++u) {
        const int e = ((b + 1) * 4 + u) * 4 + q;
        const int j = (e < m) ? idx[e] : i;
        nA[u] = *(const float4*)(h + (size_t)j * Dd + ql * 8);
        nB[u] = *(const float4*)(h + (size_t)j * Dd + ql * 8 + 4);
      }
    }
    // 4 independent DPP rotation-reductions (pure VALU, deep ILP)
    float sv[4];
#pragma unroll
    for (int u = 0; u < 4; ++u) {
      float pd = hiA.x * hvA[u].x + hiA.y * hvA[u].y + hiA.z * hvA[u].z + hiA.w * hvA[u].w
               + hiB.x * hvB[u].x + hiB.y * hvB[u].y + hiB.z * hvB[u].z + hiB.w * hvB[u].w;
      sv[u] = quarter_sum(pd);                   // quarter-uniform full dot
    }
    // per-quarter online updates (4-edge SIMD across lanes)
#pragma unroll
    for (int u = 0; u < 4; ++u) {
      const int e = (b * 4 + u) * 4 + q;
      const float s = (e < m) ? sv[u] : 0.f;
      if (s != 0.f) {                            // ref: s==0 -> masked
        const float newM = fmaxf(M, s);
        const float scale = __expf(M - newM);    // first edge: exp(-inf)=0 ✓
        const float p = __expf(s - newM);
        L = L * scale + p;
        accA.x = accA.x * scale + p * hvA[u].x;
        accA.y = accA.y * scale + p * hvA[u].y;
        accA.z = accA.z * scale + p * hvA[u].z;
        accA.w = accA.w * scale + p * hvA[u].w;
        accB.x = accB.x * scale + p * hvB[u].x;
        accB.y = accB.y * scale + p * hvB[u].y;
        accB.z = accB.z * scale + p * hvB[u].z;
        accB.w = accB.w * scale + p * hvB[u].w;
        M = newM;
      }
    }
#pragma unroll
    for (int u = 0; u < 4; ++u) { hvA[u] = nA[u]; hvB[u] = nB[u]; }
  }

  // ---- merge quarter states: xor 16 (q0<->q1, q2<->q3), then xor 32 ----
#pragma unroll
  for (int off = 16; off <= 32; off <<= 1) {
    const float Mo = __shfl_xor(M, off);
    const float Lo = __shfl_xor(L, off);
    float4 aAo, aBo;
    aAo.x = __shfl_xor(accA.x, off); aAo.y = __shfl_xor(accA.y, off);
    aAo.z = __shfl_xor(accA.z, off); aAo.w = __shfl_xor(accA.w, off);
    aBo.x = __shfl_xor(accB.x, off); aBo.y = __shfl_xor(accB.y, off);
    aBo.z = __shfl_xor(accB.z, off); aBo.w = __shfl_xor(accB.w, off);
    const float Mm = fmaxf(M, Mo);
    // guard: an empty quarter (M=-inf) contributes 0, never exp(-inf - -inf)=NaN
    const float s0 = (M  > -INFINITY) ? __expf(M  - Mm) : 0.f;
    const float s1 = (Mo > -INFINITY) ? __expf(Mo - Mm) : 0.f;
    L = L * s0 + Lo * s1;
    accA.x = accA.x * s0 + aAo.x * s1;  accA.y = accA.y * s0 + aAo.y * s1;
    accA.z = accA.z * s0 + aAo.z * s1;  accA.w = accA.w * s0 + aAo.w * s1;
    accB.x = accB.x * s0 + aBo.x * s1;  accB.y = accB.y * s0 + aBo.y * s1;
    accB.z = accB.z * s0 + aBo.z * s1;  accB.w = accB.w * s0 + aBo.w * s1;
    M = Mm;
  }
  const float inv = 1.f / L;

  if (q == 0) {                                  // lanes 0..15 write the row
    const float4 bA = *(const float4*)(bias + ql * 8);
    const float4 bB = *(const float4*)(bias + ql * 8 + 4);
    float4 oA, oB;
    oA.x = accA.x * inv + bA.x;  oA.y = accA.y * inv + bA.y;
    oA.z = accA.z * inv + bA.z;  oA.w = accA.w * inv + bA.w;
    oB.x = accB.x * inv + bB.x;  oB.y = accB.y * inv + bB.y;
    oB.z = accB.z * inv + bB.z;  oB.w = accB.w * inv + bB.w;
    *(float4*)(out + (size_t)i * Dd + ql * 8)     = oA;
    *(float4*)(out + (size_t)i * Dd + ql * 8 + 4) = oB;
  }
}

extern "C" void kernel_launch(void* const* d_in, const int* in_sizes, int n_in,
                              void* d_out, int out_size, void* d_ws, size_t ws_size,
                              hipStream_t stream) {
  const float* x     = (const float*)d_in[0];  // [1,8192,256]
  const float* graph = (const float*)d_in[1];  // [8192,8192]
  const float* W     = (const float*)d_in[2];  // [128,256]
  const float* bias  = (const float*)d_in[3];  // [128]
  float* out = (float*)d_out;                  // [1,8192,128]

  // ws layout: h (4 MB @ 0) | WT (128 KB @ 16 MB)
  float*  h  = (float*)d_ws;
  float4* WT = (float4*)((char*)d_ws + (16u << 20));

  wt_kernel<<<32, 256, 0, stream>>>(W, WT);
  h_kernel<<<Nn / 16, 256, 0, stream>>>(x, WT, h);
  gat_fused<<<Nn / 4, 256, 0, stream>>>(graph, h, bias, out);
}